// Round 1
// baseline (739.764 us; speedup 1.0000x reference)
//
#include <hip/hip_runtime.h>
#include <math.h>

#define S_LEN   512
#define HORIZON 64
#define T_LEN   (S_LEN + HORIZON)
#define F_IN    4
#define IN_DIM  36   // F_IN + E
#define HID     32

__device__ __forceinline__ float frcp(float x) { return __builtin_amdgcn_rcpf(x); }
__device__ __forceinline__ float fsig(float x) {
    x = fminf(fmaxf(x, -30.f), 30.f);
    return frcp(1.f + __expf(-x));
}
__device__ __forceinline__ float ftanh(float x) {
    x = fminf(fmaxf(x, -15.f), 15.f);
    float e = __expf(2.f * x);
    return (e - 1.f) * frcp(e + 1.f);
}

// One persistent wave. Lane l owns gate rows l and l+64 (torch order i,f,g,o):
//   lanes 0..31 : row l      = i[l],    row l+64 = g[l]
//   lanes 32..63: row l      = f[l-32], row l+64 = o[l-32]
__global__ __launch_bounds__(64, 1) void deepar_kernel(
    const float* __restrict__ X,    const float* __restrict__ y,
    const float* __restrict__ Xf,   const float* __restrict__ eps,
    const float* __restrict__ W_ye, const float* __restrict__ b_ye,
    const float* __restrict__ W_ih, const float* __restrict__ W_hh,
    const float* __restrict__ b_ih, const float* __restrict__ b_hh,
    const float* __restrict__ W_ef, const float* __restrict__ b_ef,
    const float* __restrict__ W_av, const float* __restrict__ b_av,
    const float* __restrict__ W_out, const float* __restrict__ b_out,
    const float* __restrict__ W_mu, const float* __restrict__ b_mu,
    const float* __restrict__ W_sig, const float* __restrict__ b_sig,
    float* __restrict__ out)
{
    const int lane = threadIdx.x;

    // ---- weights resident in VGPRs (per-lane rows) ----
    float wih0[IN_DIM], wih1[IN_DIM], whh0[HID], whh1[HID];
#pragma unroll
    for (int k = 0; k < IN_DIM; ++k) {
        wih0[k] = W_ih[lane * IN_DIM + k];
        wih1[k] = W_ih[(lane + 64) * IN_DIM + k];
    }
#pragma unroll
    for (int k = 0; k < HID; ++k) {
        whh0[k] = W_hh[lane * HID + k];
        whh1[k] = W_hh[(lane + 64) * HID + k];
    }
    const float bias0 = b_ih[lane] + b_hh[lane];
    const float bias1 = b_ih[lane + 64] + b_hh[lane + 64];

    // ---- collapsed-attention constants (uniform; scalar loads) ----
    float A = 0.f, B = 0.f, C1 = 0.f, C2 = 0.f, C3 = 0.f, C4 = 0.f;
#pragma unroll
    for (int k = 0; k < 32; ++k) {
        const float wef = W_ef[k], bef = b_ef[k], wav = W_av[k];
        A  += wef * wav;           B  += bef * wav;
        C1 += wef * W_out[k];      C2 += bef * W_out[k];
        C3 += wef * W_out[32 + k]; C4 += bef * W_out[32 + k];
    }
    B  += b_av[0];
    C2 += b_out[0];
    const float bmu  = b_mu[0], bsig = b_sig[0];
    const float wmu_l  = (lane < HID) ? W_mu[lane]  : 0.f;
    const float wsig_l = (lane < HID) ? W_sig[lane] : 0.f;
    const float wye_l  = (lane < HID) ? W_ye[lane]  : 0.f;
    const float bye_l  = (lane < HID) ? b_ye[lane]  : 0.f;

    __shared__ __align__(16) float ye_lds[HID];
    __shared__ __align__(16) float h_lds[HID];

    float h = 0.f, c = 0.f, ynext = 0.f;   // valid in lanes < 32 (zeroed in high lanes)

#pragma unroll 1
    for (int t = 0; t < T_LEN; ++t) {
        // uniform per-step inputs
        const float* xt = (t < S_LEN) ? (X + t * F_IN) : (Xf + (t - S_LEN) * F_IN);
        const float x0 = xt[0], x1 = xt[1], x2 = xt[2], x3 = xt[3];
        const float yin   = (t < S_LEN) ? y[t] : ynext;
        const float eps_t = eps[t];

        __syncthreads();                       // WAR vs previous iteration's reads
        if (lane < HID) {
            ye_lds[lane] = yin * wye_l + bye_l; // input_embed
            h_lds[lane]  = h;                   // h(t-1)
        }
        __syncthreads();

        // ---- LSTM gates: 2 rows x 68-dot per lane, 4 accumulators each ----
        float a0 = bias0, e0 = 0.f, f0 = 0.f, g0a = 0.f;
        float a1 = bias1, e1 = 0.f, f1 = 0.f, g1a = 0.f;
        a0 += x0 * wih0[0]; e0 += x1 * wih0[1]; f0 += x2 * wih0[2]; g0a += x3 * wih0[3];
        a1 += x0 * wih1[0]; e1 += x1 * wih1[1]; f1 += x2 * wih1[2]; g1a += x3 * wih1[3];
#pragma unroll
        for (int k = 0; k < 8; ++k) {
            const float4 v = *(const float4*)&ye_lds[4 * k];
            a0 += v.x * wih0[4 + 4*k]; e0 += v.y * wih0[5 + 4*k];
            f0 += v.z * wih0[6 + 4*k]; g0a += v.w * wih0[7 + 4*k];
            a1 += v.x * wih1[4 + 4*k]; e1 += v.y * wih1[5 + 4*k];
            f1 += v.z * wih1[6 + 4*k]; g1a += v.w * wih1[7 + 4*k];
        }
#pragma unroll
        for (int k = 0; k < 8; ++k) {
            const float4 v = *(const float4*)&h_lds[4 * k];
            a0 += v.x * whh0[4*k]; e0 += v.y * whh0[4*k + 1];
            f0 += v.z * whh0[4*k + 2]; g0a += v.w * whh0[4*k + 3];
            a1 += v.x * whh1[4*k]; e1 += v.y * whh1[4*k + 1];
            f1 += v.z * whh1[4*k + 2]; g1a += v.w * whh1[4*k + 3];
        }
        const float gate0 = (a0 + e0) + (f0 + g0a);  // i_pre (low) / f_pre (high)
        const float gate1 = (a1 + e1) + (f1 + g1a);  // g_pre (low) / o_pre (high)

        // nonlinearities: tanh(x) = 2*sigmoid(2x)-1 shares the exp
        const float s0  = fsig(gate0);
        const float arg = (lane < HID) ? 2.f * gate1 : gate1;
        const float sg  = fsig(arg);
        const float s1  = (lane < HID) ? 2.f * sg - 1.f : sg;

        const float f_sh = __shfl_down(s0, 32, 64);  // f[j] into lane j<32
        const float o_sh = __shfl_down(s1, 32, 64);  // o[j] into lane j<32
        const float c_new = f_sh * c + s0 * s1;      // lanes<32: f*c + i*tanh(g)
        const float h_new = o_sh * ftanh(c_new);
        h = (lane < HID) ? h_new : 0.f;
        c = (lane < HID) ? c_new : 0.f;

        // ---- collapsed attention ----
        const float av  = __expf(h * A + B);
        const float avh = av * h;
        float sP = av, sQ = avh;                     // inclusive scan over 32 lanes
#pragma unroll
        for (int d = 1; d < 32; d <<= 1) {
            const float pP = __shfl_up(sP, d, 64);
            const float pQ = __shfl_up(sQ, d, 64);
            if ((lane & 31) >= d) { sP += pP; sQ += pQ; }
        }
        const float P = sP - av, Q = sQ - avh;       // exclusive (strict lower mask)
        const float rden = frcp(P + 1e-9f);
        const float outv = ftanh(h * C1 + C2 + (Q * C3 + P * C4) * rden);

        // ---- mu / sigma heads: butterfly reduce over 32 lanes ----
        float pm = outv * wmu_l, ps = outv * wsig_l;
#pragma unroll
        for (int m = 16; m >= 1; m >>= 1) {
            pm += __shfl_xor(pm, m, 64);
            ps += __shfl_xor(ps, m, 64);
        }
        const float mu    = pm + bmu;
        const float sigma = __logf(1.f + __expf(ps + bsig)) + 1e-6f;
        const float ynew  = mu + sigma * eps_t;
        ynext = ynew;

        if (lane == 0) {
            out[HORIZON + t]         = mu;
            out[HORIZON + T_LEN + t] = sigma;
            if (t >= S_LEN - 1 && t < S_LEN - 1 + HORIZON)
                out[t - (S_LEN - 1)] = ynew;     // samples[511 .. 574]
        }
    }
}

extern "C" void kernel_launch(void* const* d_in, const int* in_sizes, int n_in,
                              void* d_out, int out_size, void* d_ws, size_t ws_size,
                              hipStream_t stream) {
    deepar_kernel<<<1, 64, 0, stream>>>(
        (const float*)d_in[0],  (const float*)d_in[1],  (const float*)d_in[2],
        (const float*)d_in[3],  (const float*)d_in[4],  (const float*)d_in[5],
        (const float*)d_in[6],  (const float*)d_in[7],  (const float*)d_in[8],
        (const float*)d_in[9],  (const float*)d_in[10], (const float*)d_in[11],
        (const float*)d_in[12], (const float*)d_in[13], (const float*)d_in[14],
        (const float*)d_in[15], (const float*)d_in[16], (const float*)d_in[17],
        (const float*)d_in[18], (const float*)d_in[19], (float*)d_out);
}

// Round 2
// 430.548 us; speedup vs baseline: 1.7182x; 1.7182x over previous
//
#include <hip/hip_runtime.h>
#include <math.h>

#define S_LEN   512
#define HORIZON 64
#define T_LEN   (S_LEN + HORIZON)
#define F_IN    4
#define IN_DIM  36   // F_IN + E
#define HID     32

__device__ __forceinline__ float frcp(float x) { return __builtin_amdgcn_rcpf(x); }
__device__ __forceinline__ float fsig(float x) {
    x = fminf(fmaxf(x, -30.f), 30.f);
    return frcp(1.f + __expf(-x));
}
__device__ __forceinline__ float ftanh(float x) {
    x = fminf(fmaxf(x, -15.f), 15.f);
    float e = __expf(2.f * x);
    return (e - 1.f) * frcp(e + 1.f);
}
__device__ __forceinline__ float rdlane(float v, int l) {
    return __int_as_float(__builtin_amdgcn_readlane(__float_as_int(v), l));
}

// DPP move with old=0: masked / out-of-bounds lanes produce 0.
#define DPP0(x, ctrl, rmask, bmask, bc) \
    __int_as_float(__builtin_amdgcn_update_dpp(0, __float_as_int(x), (ctrl), (rmask), (bmask), (bc)))

// One persistent wave, interleaved layout: lane 2j+p (j=0..31, p=0/1)
//   p==0: gate rows i[j] (row j)    and g[j] (row 64+j)
//   p==1: gate rows f[j] (row 32+j) and o[j] (row 96+j)
// h[j], c[j] live in lane 2j (odd lanes forced to 0).
__global__ __launch_bounds__(64, 1) void deepar_kernel(
    const float* __restrict__ X,    const float* __restrict__ y,
    const float* __restrict__ Xf,   const float* __restrict__ eps,
    const float* __restrict__ W_ye, const float* __restrict__ b_ye,
    const float* __restrict__ W_ih, const float* __restrict__ W_hh,
    const float* __restrict__ b_ih, const float* __restrict__ b_hh,
    const float* __restrict__ W_ef, const float* __restrict__ b_ef,
    const float* __restrict__ W_av, const float* __restrict__ b_av,
    const float* __restrict__ W_out, const float* __restrict__ b_out,
    const float* __restrict__ W_mu, const float* __restrict__ b_mu,
    const float* __restrict__ W_sig, const float* __restrict__ b_sig,
    float* __restrict__ out)
{
    const int lane = threadIdx.x;
    const int j    = lane >> 1;
    const int p    = lane & 1;
    const int r0   = j + 32 * p;        // i-row (p=0) / f-row (p=1)
    const int r1   = r0 + 64;           // g-row (p=0) / o-row (p=1)

    // ---- resident weights (per-lane rows) ----
    float wx0[F_IN], wx1[F_IN], whh0[HID], whh1[HID];
#pragma unroll
    for (int k = 0; k < F_IN; ++k) {
        wx0[k] = W_ih[r0 * IN_DIM + k];
        wx1[k] = W_ih[r1 * IN_DIM + k];
    }
#pragma unroll
    for (int k = 0; k < HID; ++k) {
        whh0[k] = W_hh[r0 * HID + k];
        whh1[k] = W_hh[r1 * HID + k];
    }
    // collapse the rank-1 y-embedding: sum_k yemb[k]*W_ih[r,4+k] = yin*u + v
    float u0 = 0.f, u1 = 0.f, bias0 = b_ih[r0] + b_hh[r0], bias1 = b_ih[r1] + b_hh[r1];
#pragma unroll
    for (int k = 0; k < 32; ++k) {
        const float wih0k = W_ih[r0 * IN_DIM + 4 + k];
        const float wih1k = W_ih[r1 * IN_DIM + 4 + k];
        u0 += W_ye[k] * wih0k;  bias0 += b_ye[k] * wih0k;
        u1 += W_ye[k] * wih1k;  bias1 += b_ye[k] * wih1k;
    }

    // ---- collapsed-attention constants (uniform) ----
    float A = 0.f, B = 0.f, C1 = 0.f, C2 = 0.f, C3 = 0.f, C4 = 0.f;
#pragma unroll
    for (int k = 0; k < 32; ++k) {
        const float wef = W_ef[k], bef = b_ef[k], wav = W_av[k];
        A  += wef * wav;           B  += bef * wav;
        C1 += wef * W_out[k];      C2 += bef * W_out[k];
        C3 += wef * W_out[32 + k]; C4 += bef * W_out[32 + k];
    }
    B  += b_av[0];
    C2 += b_out[0];
    const float bmu  = b_mu[0], bsig = b_sig[0];
    const float wmu_l  = p ? 0.f : W_mu[j];
    const float wsig_l = p ? 0.f : W_sig[j];

    float h = 0.f, c = 0.f, ynext = 0.f;

#pragma unroll 2
    for (int t = 0; t < T_LEN; ++t) {
        const float* xt = (t < S_LEN) ? (X + t * F_IN) : (Xf + (t - S_LEN) * F_IN);
        const float x0 = xt[0], x1 = xt[1], x2 = xt[2], x3 = xt[3];
        const float eps_t = eps[t];

        // broadcast h[0..31] (even lanes) into scalars
        float hb[HID];
#pragma unroll
        for (int k = 0; k < HID; ++k) hb[k] = rdlane(h, 2 * k);

        // ---- gate dots (yin term added last; it carries the ynext dependency) ----
        float a00 = bias0, a01 = 0.f, a02 = 0.f, a03 = 0.f;
        float a10 = bias1, a11 = 0.f, a12 = 0.f, a13 = 0.f;
        a00 += x0 * wx0[0]; a01 += x1 * wx0[1]; a02 += x2 * wx0[2]; a03 += x3 * wx0[3];
        a10 += x0 * wx1[0]; a11 += x1 * wx1[1]; a12 += x2 * wx1[2]; a13 += x3 * wx1[3];
#pragma unroll
        for (int k = 0; k < HID; k += 4) {
            a00 += hb[k]     * whh0[k];     a10 += hb[k]     * whh1[k];
            a01 += hb[k + 1] * whh0[k + 1]; a11 += hb[k + 1] * whh1[k + 1];
            a02 += hb[k + 2] * whh0[k + 2]; a12 += hb[k + 2] * whh1[k + 2];
            a03 += hb[k + 3] * whh0[k + 3]; a13 += hb[k + 3] * whh1[k + 3];
        }
        const float yin = (t < S_LEN) ? y[t] : ynext;
        const float gate0 = ((a00 + a01) + (a02 + a03)) + yin * u0; // i (even) / f (odd)
        const float gate1 = ((a10 + a11) + (a12 + a13)) + yin * u1; // g (even) / o (odd)

        // nonlinearities: tanh(x) = 2*sigmoid(2x)-1
        const float s0 = fsig(gate0);
        const float sg = fsig(p ? gate1 : 2.f * gate1);
        const float s1 = p ? sg : 2.f * sg - 1.f;

        // f,o sit in lane^1 -> quad_perm [1,0,3,2]
        const float f_sh = DPP0(s0, 0xB1, 0xF, 0xF, false);
        const float o_sh = DPP0(s1, 0xB1, 0xF, 0xF, false);
        const float c_new = f_sh * c + s0 * s1;
        const float h_new = o_sh * ftanh(c_new);
        h = p ? 0.f : h_new;
        c = p ? 0.f : c_new;

        // ---- collapsed attention: exclusive prefix sums over elements j at even lanes ----
        const float av   = __expf(h * A + B);
        const float av_e = p ? 0.f : av;
        const float avh  = av_e * h;
        float sP = av_e, sQ = avh;
        sP += DPP0(sP, 0x112, 0xF, 0xF, true);  sQ += DPP0(sQ, 0x112, 0xF, 0xF, true); // shr 1 elem
        sP += DPP0(sP, 0x114, 0xF, 0xF, true);  sQ += DPP0(sQ, 0x114, 0xF, 0xF, true); // shr 2
        sP += DPP0(sP, 0x118, 0xF, 0xF, true);  sQ += DPP0(sQ, 0x118, 0xF, 0xF, true); // shr 4
        // carry row0->row1, row2->row3: shift row-total into lane 15/47, bcast15 to rows 1,3
        float tP = DPP0(sP, 0x111, 0xF, 0xF, true), tQ = DPP0(sQ, 0x111, 0xF, 0xF, true);
        sP += DPP0(tP, 0x142, 0xA, 0xF, true);  sQ += DPP0(tQ, 0x142, 0xA, 0xF, true);
        // carry rows01 -> rows23: shift into lane 31, bcast31 to rows 2,3
        tP = DPP0(sP, 0x111, 0xF, 0xF, true);   tQ = DPP0(sQ, 0x111, 0xF, 0xF, true);
        sP += DPP0(tP, 0x143, 0xC, 0xF, true);  sQ += DPP0(tQ, 0x143, 0xC, 0xF, true);

        const float P = sP - av_e, Q = sQ - avh;     // exclusive (strict lower mask)
        const float rden = frcp(P + 1e-9f);
        const float outv = ftanh(h * C1 + C2 + (Q * C3 + P * C4) * rden);

        // ---- mu / sigma heads: DPP tree-reduce, total lands in lane 63 ----
        float pm = outv * wmu_l, ps = outv * wsig_l;
        pm += DPP0(pm, 0xB1,  0xF, 0xF, false);  ps += DPP0(ps, 0xB1,  0xF, 0xF, false); // xor1
        pm += DPP0(pm, 0x4E,  0xF, 0xF, false);  ps += DPP0(ps, 0x4E,  0xF, 0xF, false); // xor2
        pm += DPP0(pm, 0x141, 0xF, 0xF, false);  ps += DPP0(ps, 0x141, 0xF, 0xF, false); // half_mirror
        pm += DPP0(pm, 0x140, 0xF, 0xF, false);  ps += DPP0(ps, 0x140, 0xF, 0xF, false); // mirror
        pm += DPP0(pm, 0x142, 0xA, 0xF, true);   ps += DPP0(ps, 0x142, 0xA, 0xF, true);  // bcast15
        pm += DPP0(pm, 0x143, 0xC, 0xF, true);   ps += DPP0(ps, 0x143, 0xC, 0xF, true);  // bcast31

        const float mu    = rdlane(pm, 63) + bmu;
        const float sigma = __logf(1.f + __expf(rdlane(ps, 63) + bsig)) + 1e-6f;
        const float ynew  = mu + sigma * eps_t;
        ynext = ynew;

        if (lane == 0) {
            out[HORIZON + t]         = mu;
            out[HORIZON + T_LEN + t] = sigma;
            if (t >= S_LEN - 1 && t < S_LEN - 1 + HORIZON)
                out[t - (S_LEN - 1)] = ynew;     // samples[511 .. 574]
        }
    }
}

extern "C" void kernel_launch(void* const* d_in, const int* in_sizes, int n_in,
                              void* d_out, int out_size, void* d_ws, size_t ws_size,
                              hipStream_t stream) {
    deepar_kernel<<<1, 64, 0, stream>>>(
        (const float*)d_in[0],  (const float*)d_in[1],  (const float*)d_in[2],
        (const float*)d_in[3],  (const float*)d_in[4],  (const float*)d_in[5],
        (const float*)d_in[6],  (const float*)d_in[7],  (const float*)d_in[8],
        (const float*)d_in[9],  (const float*)d_in[10], (const float*)d_in[11],
        (const float*)d_in[12], (const float*)d_in[13], (const float*)d_in[14],
        (const float*)d_in[15], (const float*)d_in[16], (const float*)d_in[17],
        (const float*)d_in[18], (const float*)d_in[19], (float*)d_out);
}

// Round 3
// 297.279 us; speedup vs baseline: 2.4884x; 1.4483x over previous
//
#include <hip/hip_runtime.h>
#include <math.h>
#include <stdint.h>

#define S_LEN   512
#define HORIZON 64
#define T_LEN   (S_LEN + HORIZON)
#define F_IN    4
#define IN_DIM  36   // F_IN + E
#define HID     32

typedef float v2f __attribute__((ext_vector_type(2)));

__device__ __forceinline__ float frcp(float x) { return __builtin_amdgcn_rcpf(x); }
__device__ __forceinline__ float fsig(float x) {
    x = fminf(fmaxf(x, -30.f), 30.f);
    return frcp(1.f + __expf(-x));
}
__device__ __forceinline__ float ftanh(float x) {
    x = fminf(fmaxf(x, -15.f), 15.f);
    float e = __expf(2.f * x);
    return (e - 1.f) * frcp(e + 1.f);
}
__device__ __forceinline__ float rdlane(float v, int l) {
    return __int_as_float(__builtin_amdgcn_readlane(__float_as_int(v), l));
}
__device__ __forceinline__ void pk_fma(v2f& acc, v2f a, v2f b) {
    asm("v_pk_fma_f32 %0, %1, %2, %0" : "+v"(acc) : "v"(a), "v"(b));
}

// DPP move with old=0.
#define DPP0(x, ctrl, rmask, bmask, bc) \
    __int_as_float(__builtin_amdgcn_update_dpp(0, __float_as_int(x), (ctrl), (rmask), (bmask), (bc)))

// ============ Kernel 1: the sequential recurrence (one wave) ============
// Interleaved layout: lane 2j+p: p==0 -> rows i[j], g[j]; p==1 -> rows f[j], o[j].
// h[j], c[j] live in lane 2j (odd lanes 0).
__global__ __launch_bounds__(64, 1) void deepar_seq(
    const float* __restrict__ X,    const float* __restrict__ y,
    const float* __restrict__ Xf,   const float* __restrict__ eps,
    const float* __restrict__ W_ye, const float* __restrict__ b_ye,
    const float* __restrict__ W_ih, const float* __restrict__ W_hh,
    const float* __restrict__ b_ih, const float* __restrict__ b_hh,
    const float* __restrict__ W_ef, const float* __restrict__ b_ef,
    const float* __restrict__ W_av, const float* __restrict__ b_av,
    const float* __restrict__ W_out, const float* __restrict__ b_out,
    const float* __restrict__ W_mu, const float* __restrict__ b_mu,
    const float* __restrict__ W_sig, const float* __restrict__ b_sig,
    float* __restrict__ out, float* __restrict__ hist)
{
    const int lane = threadIdx.x;
    const int j    = lane >> 1;
    const int p    = lane & 1;
    const int r0   = j + 32 * p;
    const int r1   = r0 + 64;

    // ---- resident weights ----
    float wih0[IN_DIM], wih1[IN_DIM];
#pragma unroll
    for (int k = 0; k < 9; ++k) {
        ((float4*)wih0)[k] = ((const float4*)(W_ih + r0 * IN_DIM))[k];
        ((float4*)wih1)[k] = ((const float4*)(W_ih + r1 * IN_DIM))[k];
    }
    float whh0[HID], whh1[HID];
#pragma unroll
    for (int k = 0; k < 8; ++k) {
        ((float4*)whh0)[k] = ((const float4*)(W_hh + r0 * HID))[k];
        ((float4*)whh1)[k] = ((const float4*)(W_hh + r1 * HID))[k];
    }
    const v2f* whh0p = (const v2f*)whh0;
    const v2f* whh1p = (const v2f*)whh1;
    const v2f wx0a = ((const v2f*)wih0)[0], wx0b = ((const v2f*)wih0)[1];
    const v2f wx1a = ((const v2f*)wih1)[0], wx1b = ((const v2f*)wih1)[1];

    // collapse rank-1 y-embedding into per-row (u, bias)
    float u0 = 0.f, u1 = 0.f;
    float bias0 = b_ih[r0] + b_hh[r0], bias1 = b_ih[r1] + b_hh[r1];
#pragma unroll
    for (int k = 0; k < 32; ++k) {
        u0 += W_ye[k] * wih0[4 + k];  bias0 += b_ye[k] * wih0[4 + k];
        u1 += W_ye[k] * wih1[4 + k];  bias1 += b_ye[k] * wih1[4 + k];
    }

    // collapsed-attention constants (uniform)
    float A = 0.f, B = 0.f, C1 = 0.f, C2 = 0.f, C3 = 0.f, C4 = 0.f;
#pragma unroll
    for (int k = 0; k < 32; ++k) {
        const float wef = W_ef[k], bef = b_ef[k], wav = W_av[k];
        A  += wef * wav;           B  += bef * wav;
        C1 += wef * W_out[k];      C2 += bef * W_out[k];
        C3 += wef * W_out[32 + k]; C4 += bef * W_out[32 + k];
    }
    B  += b_av[0];
    C2 += b_out[0];
    const float bmu  = b_mu[0], bsig = b_sig[0];
    const float wmu_l  = p ? 0.f : W_mu[j];
    const float wsig_l = p ? 0.f : W_sig[j];

    __shared__ __align__(16) float h_lds[HID];
    float h = 0.f, c = 0.f, ynext = 0.f;

    // ---------- Phase A: t = 0..510 — LSTM cell only; outputs deferred ----------
#pragma unroll 2
    for (int t = 0; t < S_LEN - 1; ++t) {
        const float4 xv = *(const float4*)(X + t * F_IN);
        const float  yt = y[t];
        if (!p) h_lds[j] = h;

        const v2f xp01 = {xv.x, xv.y}, xp23 = {xv.z, xv.w};
        v2f acc00 = wx0a * xp01, acc01 = wx0b * xp23;
        v2f acc10 = wx1a * xp01, acc11 = wx1b * xp23;
#pragma unroll
        for (int k = 0; k < 8; ++k) {
            const float4 hq = ((const float4*)h_lds)[k];
            const v2f hlo = {hq.x, hq.y}, hhi = {hq.z, hq.w};
            pk_fma(acc00, whh0p[2*k],     hlo);
            pk_fma(acc01, whh0p[2*k + 1], hhi);
            pk_fma(acc10, whh1p[2*k],     hlo);
            pk_fma(acc11, whh1p[2*k + 1], hhi);
        }
        const float gate0 = bias0 + ((acc00.x + acc00.y) + (acc01.x + acc01.y)) + yt * u0;
        const float gate1 = bias1 + ((acc10.x + acc10.y) + (acc11.x + acc11.y)) + yt * u1;

        const float s0 = fsig(gate0);
        const float sg = fsig(p ? gate1 : 2.f * gate1);
        const float s1 = p ? sg : 2.f * sg - 1.f;
        const float f_sh = DPP0(s0, 0xB1, 0xF, 0xF, false);
        const float o_sh = DPP0(s1, 0xB1, 0xF, 0xF, false);
        const float c_new = f_sh * c + s0 * s1;
        const float h_new = o_sh * ftanh(c_new);
        h = p ? 0.f : h_new;
        c = p ? 0.f : c_new;

        if (!p) hist[t * HID + j] = h;   // deferred-output history
    }

    // ---------- Phase B: t = 511..575 — full step (feedback needed) ----------
#pragma unroll 1
    for (int t = S_LEN - 1; t < T_LEN; ++t) {
        const float* xt = (t < S_LEN) ? (X + t * F_IN) : (Xf + (t - S_LEN) * F_IN);
        const float4 xv = *(const float4*)xt;
        const float eps_t = eps[t];
        const float yin = (t < S_LEN) ? y[t] : ynext;
        if (!p) h_lds[j] = h;

        const v2f xp01 = {xv.x, xv.y}, xp23 = {xv.z, xv.w};
        v2f acc00 = wx0a * xp01, acc01 = wx0b * xp23;
        v2f acc10 = wx1a * xp01, acc11 = wx1b * xp23;
#pragma unroll
        for (int k = 0; k < 8; ++k) {
            const float4 hq = ((const float4*)h_lds)[k];
            const v2f hlo = {hq.x, hq.y}, hhi = {hq.z, hq.w};
            pk_fma(acc00, whh0p[2*k],     hlo);
            pk_fma(acc01, whh0p[2*k + 1], hhi);
            pk_fma(acc10, whh1p[2*k],     hlo);
            pk_fma(acc11, whh1p[2*k + 1], hhi);
        }
        const float gate0 = bias0 + ((acc00.x + acc00.y) + (acc01.x + acc01.y)) + yin * u0;
        const float gate1 = bias1 + ((acc10.x + acc10.y) + (acc11.x + acc11.y)) + yin * u1;

        const float s0 = fsig(gate0);
        const float sg = fsig(p ? gate1 : 2.f * gate1);
        const float s1 = p ? sg : 2.f * sg - 1.f;
        const float f_sh = DPP0(s0, 0xB1, 0xF, 0xF, false);
        const float o_sh = DPP0(s1, 0xB1, 0xF, 0xF, false);
        const float c_new = f_sh * c + s0 * s1;
        const float h_new = o_sh * ftanh(c_new);
        h = p ? 0.f : h_new;
        c = p ? 0.f : c_new;

        // collapsed attention (exclusive prefix over elements j at even lanes)
        const float av   = __expf(h * A + B);
        const float av_e = p ? 0.f : av;
        const float avh  = av_e * h;
        float sP = av_e, sQ = avh;
        sP += DPP0(sP, 0x112, 0xF, 0xF, true);  sQ += DPP0(sQ, 0x112, 0xF, 0xF, true);
        sP += DPP0(sP, 0x114, 0xF, 0xF, true);  sQ += DPP0(sQ, 0x114, 0xF, 0xF, true);
        sP += DPP0(sP, 0x118, 0xF, 0xF, true);  sQ += DPP0(sQ, 0x118, 0xF, 0xF, true);
        float tP = DPP0(sP, 0x111, 0xF, 0xF, true), tQ = DPP0(sQ, 0x111, 0xF, 0xF, true);
        sP += DPP0(tP, 0x142, 0xA, 0xF, true);  sQ += DPP0(tQ, 0x142, 0xA, 0xF, true);
        tP = DPP0(sP, 0x111, 0xF, 0xF, true);   tQ = DPP0(sQ, 0x111, 0xF, 0xF, true);
        sP += DPP0(tP, 0x143, 0xC, 0xF, true);  sQ += DPP0(tQ, 0x143, 0xC, 0xF, true);

        const float P = sP - av_e, Q = sQ - avh;
        const float rden = frcp(P + 1e-9f);
        const float outv = ftanh(h * C1 + C2 + (Q * C3 + P * C4) * rden);

        // mu / sigma: DPP tree-reduce, total in lane 63
        float pm = outv * wmu_l, ps = outv * wsig_l;
        pm += DPP0(pm, 0xB1,  0xF, 0xF, false);  ps += DPP0(ps, 0xB1,  0xF, 0xF, false);
        pm += DPP0(pm, 0x4E,  0xF, 0xF, false);  ps += DPP0(ps, 0x4E,  0xF, 0xF, false);
        pm += DPP0(pm, 0x141, 0xF, 0xF, false);  ps += DPP0(ps, 0x141, 0xF, 0xF, false);
        pm += DPP0(pm, 0x140, 0xF, 0xF, false);  ps += DPP0(ps, 0x140, 0xF, 0xF, false);
        pm += DPP0(pm, 0x142, 0xA, 0xF, true);   ps += DPP0(ps, 0x142, 0xA, 0xF, true);
        pm += DPP0(pm, 0x143, 0xC, 0xF, true);   ps += DPP0(ps, 0x143, 0xC, 0xF, true);

        const float mu    = rdlane(pm, 63) + bmu;
        const float sigma = __logf(1.f + __expf(rdlane(ps, 63) + bsig)) + 1e-6f;
        const float ynew  = mu + sigma * eps_t;
        ynext = ynew;

        if (lane == 0) {
            out[HORIZON + t]         = mu;
            out[HORIZON + T_LEN + t] = sigma;
            if (t >= S_LEN - 1 && t < S_LEN - 1 + HORIZON)
                out[t - (S_LEN - 1)] = ynew;
        }
    }
}

// ============ Kernel 2: parallel deferred outputs for t = 0..510 ============
__global__ __launch_bounds__(256) void deepar_par(
    const float* __restrict__ hist,
    const float* __restrict__ W_ef, const float* __restrict__ b_ef,
    const float* __restrict__ W_av, const float* __restrict__ b_av,
    const float* __restrict__ W_out, const float* __restrict__ b_out,
    const float* __restrict__ W_mu, const float* __restrict__ b_mu,
    const float* __restrict__ W_sig, const float* __restrict__ b_sig,
    float* __restrict__ out)
{
    const int gid = (blockIdx.x * 256 + threadIdx.x) >> 5;   // one step per 32 lanes
    const int l   = threadIdx.x & 31;
    if (gid >= S_LEN - 1) return;

    float A = 0.f, B = 0.f, C1 = 0.f, C2 = 0.f, C3 = 0.f, C4 = 0.f;
#pragma unroll
    for (int k = 0; k < 32; ++k) {
        const float wef = W_ef[k], bef = b_ef[k], wav = W_av[k];
        A  += wef * wav;           B  += bef * wav;
        C1 += wef * W_out[k];      C2 += bef * W_out[k];
        C3 += wef * W_out[32 + k]; C4 += bef * W_out[32 + k];
    }
    B  += b_av[0];
    C2 += b_out[0];

    const float hj  = hist[gid * HID + l];
    const float av  = __expf(hj * A + B);
    const float avh = av * hj;
    float sP = av, sQ = avh;
#pragma unroll
    for (int d = 1; d < 32; d <<= 1) {
        const float pP = __shfl_up(sP, d, 32);
        const float pQ = __shfl_up(sQ, d, 32);
        if (l >= d) { sP += pP; sQ += pQ; }
    }
    const float P = sP - av, Q = sQ - avh;
    const float rden = frcp(P + 1e-9f);
    const float outv = ftanh(hj * C1 + C2 + (Q * C3 + P * C4) * rden);

    float pm = outv * W_mu[l], ps = outv * W_sig[l];
#pragma unroll
    for (int m = 16; m >= 1; m >>= 1) {
        pm += __shfl_xor(pm, m, 32);
        ps += __shfl_xor(ps, m, 32);
    }
    if (l == 0) {
        out[HORIZON + gid]         = pm + b_mu[0];
        out[HORIZON + T_LEN + gid] = __logf(1.f + __expf(ps + b_sig[0])) + 1e-6f;
    }
}

extern "C" void kernel_launch(void* const* d_in, const int* in_sizes, int n_in,
                              void* d_out, int out_size, void* d_ws, size_t ws_size,
                              hipStream_t stream) {
    float* hist = (float*)d_ws;   // (S_LEN-1) x HID floats

    deepar_seq<<<1, 64, 0, stream>>>(
        (const float*)d_in[0],  (const float*)d_in[1],  (const float*)d_in[2],
        (const float*)d_in[3],  (const float*)d_in[4],  (const float*)d_in[5],
        (const float*)d_in[6],  (const float*)d_in[7],  (const float*)d_in[8],
        (const float*)d_in[9],  (const float*)d_in[10], (const float*)d_in[11],
        (const float*)d_in[12], (const float*)d_in[13], (const float*)d_in[14],
        (const float*)d_in[15], (const float*)d_in[16], (const float*)d_in[17],
        (const float*)d_in[18], (const float*)d_in[19], (float*)d_out, hist);

    const int groups = S_LEN - 1;
    const int blocks = (groups * 32 + 255) / 256;
    deepar_par<<<blocks, 256, 0, stream>>>(
        hist,
        (const float*)d_in[10], (const float*)d_in[11],
        (const float*)d_in[12], (const float*)d_in[13],
        (const float*)d_in[14], (const float*)d_in[15],
        (const float*)d_in[16], (const float*)d_in[17],
        (const float*)d_in[18], (const float*)d_in[19], (float*)d_out);
}